// Round 1
// baseline (511.779 us; speedup 1.0000x reference)
//
#include <hip/hip_runtime.h>

// JBF block: M = B*Dout*H*W = 2*16*128*128 = 524288 voxels.
// Each voxel: dk = relu(conv3d_555_333(dom)+bd), rk = relu(conv3d(guide)+br),
//             w = dk*rk + 1e-10 ; out = sum(w * x_nbr) / sum(w).
// dom/guide records are 125 contiguous floats per voxel (500 B).

#define VPB 64          // voxels per block == block size (1 wave)
#define REC 125         // floats per record
#define CHUNK_F4 2000   // VPB*REC/4 float4s per staged chunk (32000 B)

__global__ __launch_bounds__(64) void jbf_kernel(
    const float* __restrict__ x,      // [2,1,18,128,128]
    const float* __restrict__ dom,    // [M,125]
    const float* __restrict__ gui,    // [M,125]
    const float* __restrict__ dom_w,  // [27]
    const float* __restrict__ dom_b,  // [1]
    const float* __restrict__ rng_w,  // [27]
    const float* __restrict__ rng_b,  // [1]
    float* __restrict__ out)          // [M]
{
    __shared__ float sm[VPB * REC];   // 32000 B, reused dom -> guide
    const int lane = threadIdx.x;
    const int m0   = blockIdx.x * VPB;
    const int m    = m0 + lane;

    // conv weights/biases: uniform addresses -> scalar loads
    float wd[27], wr[27];
#pragma unroll
    for (int i = 0; i < 27; ++i) { wd[i] = dom_w[i]; wr[i] = rng_w[i]; }
    const float bd = dom_b[0], br = rng_b[0];

    // ---- stage domain chunk (coalesced float4, 16B-aligned: m0*500 % 16 == 0) ----
    {
        const float4* src = (const float4*)(dom + (size_t)m0 * REC);
        float4* dst = (float4*)sm;
#pragma unroll
        for (int k = 0; k < 31; ++k) dst[k * 64 + lane] = src[k * 64 + lane];
        if (lane < CHUNK_F4 - 31 * 64) dst[31 * 64 + lane] = src[31 * 64 + lane];
    }
    __syncthreads();

    // ---- dk = conv(dom record) : 729 FMAs, LDS reads stride-125 (bank perm) ----
    float dkv[27];
#pragma unroll
    for (int i = 0; i < 27; ++i) dkv[i] = 0.f;
    {
        const float* rec = sm + lane * REC;
#pragma unroll
        for (int z = 0; z < 5; ++z)
#pragma unroll
            for (int r = 0; r < 5; ++r)
#pragma unroll
                for (int c = 0; c < 5; ++c) {
                    const float v = rec[z * 25 + r * 5 + c];
#pragma unroll
                    for (int i = 0; i < 3; ++i) {
                        const int a = z - i; if (a < 0 || a > 2) continue;
#pragma unroll
                        for (int j = 0; j < 3; ++j) {
                            const int b = r - j; if (b < 0 || b > 2) continue;
#pragma unroll
                            for (int l = 0; l < 3; ++l) {
                                const int cc = c - l; if (cc < 0 || cc > 2) continue;
                                dkv[(i * 3 + j) * 3 + l] =
                                    fmaf(v, wd[(a * 3 + b) * 3 + cc],
                                         dkv[(i * 3 + j) * 3 + l]);
                            }
                        }
                    }
                }
    }
    __syncthreads();   // before overwriting sm

    // ---- stage guide chunk ----
    {
        const float4* src = (const float4*)(gui + (size_t)m0 * REC);
        float4* dst = (float4*)sm;
#pragma unroll
        for (int k = 0; k < 31; ++k) dst[k * 64 + lane] = src[k * 64 + lane];
        if (lane < CHUNK_F4 - 31 * 64) dst[31 * 64 + lane] = src[31 * 64 + lane];
    }
    __syncthreads();

    // ---- rk = conv(guide record) ----
    float rkv[27];
#pragma unroll
    for (int i = 0; i < 27; ++i) rkv[i] = 0.f;
    {
        const float* rec = sm + lane * REC;
#pragma unroll
        for (int z = 0; z < 5; ++z)
#pragma unroll
            for (int r = 0; r < 5; ++r)
#pragma unroll
                for (int c = 0; c < 5; ++c) {
                    const float v = rec[z * 25 + r * 5 + c];
#pragma unroll
                    for (int i = 0; i < 3; ++i) {
                        const int a = z - i; if (a < 0 || a > 2) continue;
#pragma unroll
                        for (int j = 0; j < 3; ++j) {
                            const int b = r - j; if (b < 0 || b > 2) continue;
#pragma unroll
                            for (int l = 0; l < 3; ++l) {
                                const int cc = c - l; if (cc < 0 || cc > 2) continue;
                                rkv[(i * 3 + j) * 3 + l] =
                                    fmaf(v, wr[(a * 3 + b) * 3 + cc],
                                         rkv[(i * 3 + j) * 3 + l]);
                            }
                        }
                    }
                }
    }

    // ---- epilogue: weights * x-neighborhood, normalize ----
    // m = ((b*16 + dz)*128 + h)*128 + w
    const int w_  = m & 127;
    const int h_  = (m >> 7) & 127;
    const int dz  = (m >> 14) & 15;
    const int b_  = m >> 18;

    float num = 0.f, den = 0.f;
#pragma unroll
    for (int i = 0; i < 3; ++i) {
        const int zz = b_ * 18 + dz + i;   // depth always in range
#pragma unroll
        for (int j = 0; j < 3; ++j) {
            const int hh = h_ - 1 + j;
            const bool okh = (unsigned)hh < 128u;
#pragma unroll
            for (int l = 0; l < 3; ++l) {
                const int ww = w_ - 1 + l;
                const bool ok = okh && ((unsigned)ww < 128u);
                const float xv = ok ? x[((size_t)zz * 128 + hh) * 128 + ww] : 0.f;
                const float wv = fmaxf(dkv[(i * 3 + j) * 3 + l] + bd, 0.f) *
                                 fmaxf(rkv[(i * 3 + j) * 3 + l] + br, 0.f) + 1e-10f;
                den += wv;
                num = fmaf(wv, xv, num);
            }
        }
    }
    out[m] = num / den;
}

extern "C" void kernel_launch(void* const* d_in, const int* in_sizes, int n_in,
                              void* d_out, int out_size, void* d_ws, size_t ws_size,
                              hipStream_t stream) {
    const float* x     = (const float*)d_in[0];
    const float* dom   = (const float*)d_in[1];
    const float* gui   = (const float*)d_in[2];
    const float* dom_w = (const float*)d_in[3];
    const float* dom_b = (const float*)d_in[4];
    const float* rng_w = (const float*)d_in[5];
    const float* rng_b = (const float*)d_in[6];
    float* outp = (float*)d_out;

    const int M = in_sizes[1] / REC;      // 524288
    const int grid = M / VPB;             // 8192 blocks
    jbf_kernel<<<grid, VPB, 0, stream>>>(x, dom, gui, dom_w, dom_b,
                                         rng_w, rng_b, outp);
}